// Round 4
// baseline (64611.206 us; speedup 1.0000x reference)
//
#include <hip/hip_runtime.h>
#include <hip/hip_bf16.h>

// ---------------------------------------------------------------------------
// MPNN_block_seperate — fp32, high-ILP conv core.
// Round-3 counters: conv kernels latency-bound (VALUBusy 36%, Occupancy 12%).
// Fix: 4co x 9l per thread (108 FMA per 6 ds_read_b128), weights in LDS as
// [ci][co][r] (contiguous 12 floats/thread), register-resident pooling (no
// s_z), LDS 28.9KB, __launch_bounds__(256,4) -> 4 waves/SIMD.
// Orchestration identical to round 3 (two-pass BN, batch-chunked block1->2).
// ---------------------------------------------------------------------------

#define TPB 256
#define CO_T 128
#define L_T  64
#define CIC  16

// stats block offsets (floats)
#define RAW1 0
#define FIN1 512
#define RAW2 1024
#define FIN2 1280
#define RAW3 1536
#define FIN3 2048
#define RAWG 2560
#define ST_FLOATS 2688

// ---------------------------------------------------------------------------
// conv1: reads x[bq][s][n][d] directly (in[ci][l] = x[bq][l][n][ci]).
// MODE 0 = stats (raw), MODE 1 = apply (BN+ReLU+pool -> P1 chunk [bl][256][129])
// ---------------------------------------------------------------------------
template<int MODE>
__global__ __launch_bounds__(TPB, 4) void conv1_k(const float* __restrict__ x,
                                                  const float* __restrict__ w,
                                                  const float* __restrict__ fin,
                                                  const float* __restrict__ g,
                                                  const float* __restrict__ bt,
                                                  float* __restrict__ out,
                                                  float* __restrict__ raw,
                                                  int bn0)
{
    __shared__ float s_in[CIC * 68];          //  4352 B
    __shared__ float s_w[CIC * CO_T * 3];     // 24576 B
    int bn = bn0 + blockIdx.z;
    int bq = bn >> 6, n = bn & 63;
    int co0 = blockIdx.y * CO_T;
    int l0  = blockIdx.x * L_T;
    int tid = threadIdx.x;
    int lt = tid & 7, cg = tid >> 3;          // 8 l-groups x 32 co-groups
    int ll = lt * 8;
    const float* xb = x + (size_t)bq * 1048576 + (size_t)n * 64;

    float z[4][9] = {};                        // z[c4][k], k -> l = l0+ll+k-1
#pragma unroll 1
    for (int ci0 = 0; ci0 < 64; ci0 += CIC) {
        for (int idx = tid; idx < 68 * 16; idx += TPB) {
            int c = idx & 15, jj = idx >> 4;
            int gl = l0 - 2 + jj;              // pad=1: gl = l0-1-pad+jj
            float v = 0.f;
            if (gl >= 0 && gl < 256) v = xb[(size_t)gl * 4096 + ci0 + c];
            s_in[c * 68 + jj] = v;
        }
        for (int idx = tid; idx < CO_T * 64; idx += TPB) {
            int r = idx & 3;
            if (r < 3) {
                int c = idx >> 6, cc = (idx >> 2) & 15;
                s_w[cc * (CO_T * 3) + c * 3 + r] =
                    w[((size_t)(co0 + c) * 64 + ci0 + cc) * 3 + r];
            }
        }
        __syncthreads();
#pragma unroll
        for (int cc = 0; cc < CIC; cc++) {
            const float* ip = &s_in[cc * 68 + ll];
            float iv[12];
#pragma unroll
            for (int t = 0; t < 12; t += 4) {
                float4 v4 = *(const float4*)(ip + t);
                iv[t] = v4.x; iv[t+1] = v4.y; iv[t+2] = v4.z; iv[t+3] = v4.w;
            }
            const float* wp = &s_w[cc * (CO_T * 3) + cg * 12];
            float wv[12];
#pragma unroll
            for (int t = 0; t < 12; t += 4) {
                float4 v4 = *(const float4*)(wp + t);
                wv[t] = v4.x; wv[t+1] = v4.y; wv[t+2] = v4.z; wv[t+3] = v4.w;
            }
#pragma unroll
            for (int c4 = 0; c4 < 4; c4++)
#pragma unroll
                for (int k = 0; k < 9; k++)
                    z[c4][k] += wv[c4*3] * iv[k] + wv[c4*3+1] * iv[k+1]
                              + wv[c4*3+2] * iv[k+2];
        }
        __syncthreads();
    }
    if (MODE == 0) {
#pragma unroll
        for (int c4 = 0; c4 < 4; c4++) {
            float s1 = 0.f, s2 = 0.f;
#pragma unroll
            for (int k = 1; k < 9; k++) { float v = z[c4][k]; s1 += v; s2 += v * v; }
            s1 += __shfl_xor(s1, 1); s2 += __shfl_xor(s2, 1);
            s1 += __shfl_xor(s1, 2); s2 += __shfl_xor(s2, 2);
            s1 += __shfl_xor(s1, 4); s2 += __shfl_xor(s2, 4);
            if (lt == 0) {
                int co = co0 + cg * 4 + c4;
                atomicAdd(&raw[co], s1);
                atomicAdd(&raw[256 + co], s2);
            }
        }
    } else {
#pragma unroll
        for (int c4 = 0; c4 < 4; c4++) {
            int co = co0 + cg * 4 + c4;
            float scale = g[co] * fin[256 + co];
            float shift = bt[co] - fin[co] * scale;
            float zb[9];
#pragma unroll
            for (int k = 0; k < 9; k++) {
                int lz = l0 + ll + k - 1;
                float v = z[c4][k] * scale + shift;
                v = v > 0.f ? v : 0.f;
                zb[k] = (lz >= 0) ? v : 0.f;
            }
            float* ob = out + ((size_t)blockIdx.z * 256 + co) * 129;
            int jb = (l0 >> 1) + lt * 4;
#pragma unroll
            for (int jj = 0; jj < 4; jj++)
                ob[jb + jj] = fmaxf(zb[2*jj], zb[2*jj+1]);
            if (l0 == 192 && lt == 7)
                ob[128] = zb[8];               // window j=128 uses only z[255]
        }
    }
}

// ---------------------------------------------------------------------------
// generic conv: reads in[b][CI][Lin] fp32.
// MODE 0 = stats; MODE 1 = apply. EPI 0: out[(bn0+bz)*CO+co][Lp];
// EPI 1: fold to spa[((bq*72+tc)*64+n)*128+f], linear=co*36+j.
// ---------------------------------------------------------------------------
template<int MODE, int EPI>
__global__ __launch_bounds__(TPB, 4) void convG_k(const float* __restrict__ in,
                                                  const float* __restrict__ w,
                                                  const float* __restrict__ fin,
                                                  const float* __restrict__ g,
                                                  const float* __restrict__ bt,
                                                  float* __restrict__ out,
                                                  float* __restrict__ raw,
                                                  int CI, int CO, int Lin, int pad,
                                                  int Lout, int Lp, int bn0)
{
    __shared__ float s_in[CIC * 68];
    __shared__ float s_w[CIC * CO_T * 3];
    int bz  = blockIdx.z;
    int co0 = blockIdx.y * CO_T;
    int l0  = blockIdx.x * L_T;
    int tid = threadIdx.x;
    int lt = tid & 7, cg = tid >> 3;
    int ll = lt * 8;
    const float* inb = in + (size_t)bz * CI * Lin;

    float z[4][9] = {};
    for (int ci0 = 0; ci0 < CI; ci0 += CIC) {
        for (int idx = tid; idx < 68 * 16; idx += TPB) {
            int c = idx / 68, jj = idx - c * 68;
            int gl = l0 - 1 - pad + jj;
            float v = 0.f;
            if (gl >= 0 && gl < Lin) v = inb[(size_t)(ci0 + c) * Lin + gl];
            s_in[c * 68 + jj] = v;
        }
        for (int idx = tid; idx < CO_T * 64; idx += TPB) {
            int r = idx & 3;
            if (r < 3) {
                int c = idx >> 6, cc = (idx >> 2) & 15;
                s_w[cc * (CO_T * 3) + c * 3 + r] =
                    w[((size_t)(co0 + c) * CI + ci0 + cc) * 3 + r];
            }
        }
        __syncthreads();
#pragma unroll
        for (int cc = 0; cc < CIC; cc++) {
            const float* ip = &s_in[cc * 68 + ll];
            float iv[12];
#pragma unroll
            for (int t = 0; t < 12; t += 4) {
                float4 v4 = *(const float4*)(ip + t);
                iv[t] = v4.x; iv[t+1] = v4.y; iv[t+2] = v4.z; iv[t+3] = v4.w;
            }
            const float* wp = &s_w[cc * (CO_T * 3) + cg * 12];
            float wv[12];
#pragma unroll
            for (int t = 0; t < 12; t += 4) {
                float4 v4 = *(const float4*)(wp + t);
                wv[t] = v4.x; wv[t+1] = v4.y; wv[t+2] = v4.z; wv[t+3] = v4.w;
            }
#pragma unroll
            for (int c4 = 0; c4 < 4; c4++)
#pragma unroll
                for (int k = 0; k < 9; k++)
                    z[c4][k] += wv[c4*3] * iv[k] + wv[c4*3+1] * iv[k+1]
                              + wv[c4*3+2] * iv[k+2];
        }
        __syncthreads();
    }
    if (MODE == 0) {
#pragma unroll
        for (int c4 = 0; c4 < 4; c4++) {
            float s1 = 0.f, s2 = 0.f;
#pragma unroll
            for (int k = 1; k < 9; k++) {
                int lz = l0 + ll + k - 1;
                if (lz < Lout) { float v = z[c4][k]; s1 += v; s2 += v * v; }
            }
            s1 += __shfl_xor(s1, 1); s2 += __shfl_xor(s2, 1);
            s1 += __shfl_xor(s1, 2); s2 += __shfl_xor(s2, 2);
            s1 += __shfl_xor(s1, 4); s2 += __shfl_xor(s2, 4);
            if (lt == 0) {
                int co = co0 + cg * 4 + c4;
                atomicAdd(&raw[co], s1);
                atomicAdd(&raw[CO + co], s2);
            }
        }
    } else {
#pragma unroll
        for (int c4 = 0; c4 < 4; c4++) {
            int co = co0 + cg * 4 + c4;
            float scale = g[co] * fin[CO + co];
            float shift = bt[co] - fin[co] * scale;
            float zb[8];
#pragma unroll
            for (int k = 0; k < 8; k++) {
                int lz = l0 + ll + k - 1;
                float v = z[c4][k] * scale + shift;
                v = v > 0.f ? v : 0.f;
                zb[k] = (lz >= 0 && lz < Lout) ? v : 0.f;
            }
            int jb = (l0 >> 1) + lt * 4;
#pragma unroll
            for (int jj = 0; jj < 4; jj++) {
                int j = jb + jj;
                if (j >= Lp) continue;
                float v = fmaxf(zb[2*jj], zb[2*jj+1]);
                if (EPI == 0) {
                    out[((size_t)(bn0 + bz) * CO + co) * (size_t)Lp + j] = v;
                } else {
                    int linear = co * 36 + j;
                    int tc = linear >> 7, f = linear & 127;
                    int bq = bz >> 6, n = bz & 63;
                    out[(((size_t)bq * 72 + tc) * 64 + n) * 128 + f] = v;
                }
            }
        }
    }
}

__global__ __launch_bounds__(TPB) void bn_fin_k(const float* __restrict__ raw,
                                                float* __restrict__ fin, int C, float invN)
{
    int c = threadIdx.x + blockIdx.x * TPB;
    if (c < C) {
        float m = raw[c] * invN;
        float v = raw[C + c] * invN - m * m;
        fin[c] = m;
        fin[C + c] = rsqrtf(v + 1e-5f);
    }
}

// ---------------- nf = spa @ map_w^T + map_b ----------------
__global__ __launch_bounds__(TPB) void gemm_nf_k(const float* __restrict__ A,
                                                 const float* __restrict__ W,
                                                 const float* __restrict__ bias,
                                                 float* __restrict__ out)
{
    __shared__ float s_a[64 * 33];
    __shared__ float s_w[128 * 33];
    int r0 = blockIdx.x * 64;
    int tid = threadIdx.x;
    int rg = tid >> 4, cgc = tid & 15;
    float acc[4][8];
#pragma unroll
    for (int i = 0; i < 8; i++) {
        float bv = bias[cgc + 16 * i];
#pragma unroll
        for (int j = 0; j < 4; j++) acc[j][i] = bv;
    }
    for (int k0 = 0; k0 < 128; k0 += 32) {
        for (int idx = tid; idx < 64 * 32; idx += TPB) {
            int r = idx >> 5, kk = idx & 31;
            s_a[r * 33 + kk] = A[(size_t)(r0 + r) * 128 + k0 + kk];
        }
        for (int idx = tid; idx < 128 * 32; idx += TPB) {
            int f = idx >> 5, kk = idx & 31;
            s_w[f * 33 + kk] = W[(size_t)f * 128 + k0 + kk];
        }
        __syncthreads();
#pragma unroll
        for (int kk = 0; kk < 32; kk++) {
            float av[4];
#pragma unroll
            for (int j = 0; j < 4; j++) av[j] = s_a[(rg * 4 + j) * 33 + kk];
#pragma unroll
            for (int i = 0; i < 8; i++) {
                float wv = s_w[(cgc + 16 * i) * 33 + kk];
#pragma unroll
                for (int j = 0; j < 4; j++) acc[j][i] += av[j] * wv;
            }
        }
        __syncthreads();
    }
#pragma unroll
    for (int j = 0; j < 4; j++) {
        size_t row = (size_t)(r0 + rg * 4 + j) * 128;
#pragma unroll
        for (int i = 0; i < 8; i++) out[row + cgc + 16 * i] = acc[j][i];
    }
}

// ---------------- graph kernel (adj/softmax/G/out) per b' slice ----------------
__global__ __launch_bounds__(TPB) void graph_k(const float* __restrict__ nf,
                                               const float* __restrict__ theta_w,
                                               const float* __restrict__ theta_b,
                                               float* __restrict__ gout)
{
    __shared__ float s_nfT[128 * 66];
    __shared__ float s_adj[64 * 64];
    __shared__ float s_red[256];
    __shared__ float s_rmax[64];
    __shared__ float s_rsum[64];
    float* s_G = s_nfT;

    int bp = blockIdx.x;
    int tid = threadIdx.x;
    const float* nfb = nf + (size_t)bp * 64 * 128;

    for (int idx = tid; idx < 64 * 128; idx += TPB) {
        int n = idx >> 7, f = idx & 127;
        s_nfT[f * 66 + n] = nfb[idx];
    }
    __syncthreads();

    int mg = tid & 15, ng = tid >> 4;
    {
        float a[4][4] = {};
#pragma unroll 4
        for (int f = 0; f < 128; f++) {
            float nv[4], mv[4];
#pragma unroll
            for (int j = 0; j < 4; j++) nv[j] = s_nfT[f * 66 + ng * 4 + j];
#pragma unroll
            for (int i = 0; i < 4; i++) mv[i] = s_nfT[f * 66 + mg * 4 + i];
#pragma unroll
            for (int j = 0; j < 4; j++)
#pragma unroll
                for (int i = 0; i < 4; i++) a[j][i] += nv[j] * mv[i];
        }
#pragma unroll
        for (int j = 0; j < 4; j++)
#pragma unroll
            for (int i = 0; i < 4; i++) {
                int n = ng * 4 + j, m = mg * 4 + i;
                float v = a[j][i];
                if (n == m) v -= 1e8f;
                v = v > 0.f ? v : 0.01f * v;
                s_adj[n * 64 + m] = v;
            }
    }
    __syncthreads();
    {
        int n = tid >> 2, q = tid & 3;
        float mx = -3.0e38f;
        for (int m = q * 16; m < q * 16 + 16; m++) mx = fmaxf(mx, s_adj[n * 64 + m]);
        s_red[n * 4 + q] = mx;
    }
    __syncthreads();
    if (tid < 64)
        s_rmax[tid] = fmaxf(fmaxf(s_red[tid * 4], s_red[tid * 4 + 1]),
                            fmaxf(s_red[tid * 4 + 2], s_red[tid * 4 + 3]));
    __syncthreads();
    {
        int n = tid >> 2, q = tid & 3;
        float mx = s_rmax[n];
        float sm = 0.f;
        for (int m = q * 16; m < q * 16 + 16; m++) {
            float e = __expf(s_adj[n * 64 + m] - mx);
            s_adj[n * 64 + m] = e;
            sm += e;
        }
        s_red[n * 4 + q] = sm;
    }
    __syncthreads();
    if (tid < 64)
        s_rsum[tid] = 1.0f / (s_red[tid * 4] + s_red[tid * 4 + 1] +
                              s_red[tid * 4 + 2] + s_red[tid * 4 + 3]);
    __syncthreads();
    {
        int n = tid >> 2, q = tid & 3;
        float inv = s_rsum[n];
        for (int m = q * 16; m < q * 16 + 16; m++)
            s_adj[n * 64 + m] = s_adj[n * 64 + m] * inv + ((n == m) ? 1.f : 0.f);
    }
    __syncthreads();
    {
        float ga[4][4] = {};
#pragma unroll 4
        for (int f = 0; f < 128; f++) {
            float mv[4], tv[4];
#pragma unroll
            for (int j = 0; j < 4; j++) mv[j] = s_nfT[f * 66 + ng * 4 + j];
#pragma unroll
            for (int i = 0; i < 4; i++) tv[i] = theta_w[(size_t)(mg + 16 * i) * 128 + f];
#pragma unroll
            for (int j = 0; j < 4; j++)
#pragma unroll
                for (int i = 0; i < 4; i++) ga[j][i] += mv[j] * tv[i];
        }
        __syncthreads();
#pragma unroll
        for (int j = 0; j < 4; j++)
#pragma unroll
            for (int i = 0; i < 4; i++)
                s_G[(ng * 4 + j) * 66 + mg + 16 * i] = ga[j][i];
    }
    __syncthreads();
    {
        float oacc[4][4];
#pragma unroll
        for (int i = 0; i < 4; i++) {
            float bv = theta_b[mg + 16 * i];
#pragma unroll
            for (int j = 0; j < 4; j++) oacc[j][i] = bv;
        }
#pragma unroll 4
        for (int m = 0; m < 64; m++) {
            float av[4], gv[4];
#pragma unroll
            for (int j = 0; j < 4; j++) av[j] = s_adj[(ng * 4 + j) * 64 + m];
#pragma unroll
            for (int i = 0; i < 4; i++) gv[i] = s_G[m * 66 + mg + 16 * i];
#pragma unroll
            for (int j = 0; j < 4; j++)
#pragma unroll
                for (int i = 0; i < 4; i++) oacc[j][i] += av[j] * gv[i];
        }
        float* gb = gout + (size_t)bp * 64 * 64;
#pragma unroll
        for (int j = 0; j < 4; j++)
#pragma unroll
            for (int i = 0; i < 4; i++)
                gb[(size_t)(ng * 4 + j) * 64 + mg + 16 * i] = oacc[j][i];
    }
}

// ---------------- stats over gout [73728][64] per feature o ----------------
__global__ __launch_bounds__(TPB) void stat_inner_k(const float* __restrict__ y,
                                                    float* __restrict__ raw,
                                                    int rows_per_block)
{
    int tid = threadIdx.x;
    int o = tid & 63, rr = tid >> 6;
    long r0 = (long)blockIdx.x * rows_per_block;
    float s1 = 0.f, s2 = 0.f;
    for (int r = rr; r < rows_per_block; r += 4) {
        float v = y[(r0 + r) * 64 + o];
        s1 += v; s2 += v * v;
    }
    __shared__ float b1[TPB], b2[TPB];
    b1[tid] = s1; b2[tid] = s2; __syncthreads();
    if (tid < 128) { b1[tid] += b1[tid + 128]; b2[tid] += b2[tid + 128]; }
    __syncthreads();
    if (tid < 64) {
        atomicAdd(&raw[o], b1[tid] + b1[tid + 64]);
        atomicAdd(&raw[64 + o], b2[tid] + b2[tid + 64]);
    }
}

// ---------------- final BN + leaky + pair mean -> [16][36][64][64] ----------------
__global__ __launch_bounds__(TPB) void final_k(const float* __restrict__ gout,
                                               const float* __restrict__ raw,
                                               const float* __restrict__ g,
                                               const float* __restrict__ b,
                                               float* __restrict__ out)
{
    long idx = (long)blockIdx.x * TPB + threadIdx.x;
    if (idx >= 2359296L) return;
    int o = (int)(idx & 63);
    long t = idx >> 6;
    int n = (int)(t & 63);
    long t2 = t >> 6;
    long wd = t2 % 36;
    long bb = t2 / 36;
    const float invN = 1.0f / 73728.0f;
    float m = raw[o] * invN;
    float var = raw[64 + o] * invN - m * m;
    float scale = g[o] * rsqrtf(var + 1e-5f);
    float shift = b[o] - m * scale;
    long bp = bb * 72 + wd * 2;
    float v0 = gout[(bp * 64 + n) * 64 + o] * scale + shift;
    float v1 = gout[((bp + 1) * 64 + n) * 64 + o] * scale + shift;
    v0 = v0 > 0.f ? v0 : 0.01f * v0;
    v1 = v1 > 0.f ? v1 : 0.01f * v1;
    out[idx] = 0.5f * (v0 + v1);
}

// ---------------------------------------------------------------------------
extern "C" void kernel_launch(void* const* d_in, const int* in_sizes, int n_in,
                              void* d_out, int out_size, void* d_ws, size_t ws_size,
                              hipStream_t stream)
{
    (void)in_sizes; (void)n_in; (void)out_size;
    const float* x    = (const float*)d_in[0];
    const float* c1w  = (const float*)d_in[1];
    const float* g1   = (const float*)d_in[2];
    const float* b1   = (const float*)d_in[3];
    const float* c2w  = (const float*)d_in[4];
    const float* g2   = (const float*)d_in[5];
    const float* b2   = (const float*)d_in[6];
    const float* c3w  = (const float*)d_in[7];
    const float* g3   = (const float*)d_in[8];
    const float* b3   = (const float*)d_in[9];
    const float* mapw = (const float*)d_in[10];
    const float* mapb = (const float*)d_in[11];
    const float* thw  = (const float*)d_in[12];
    const float* thb  = (const float*)d_in[13];
    const float* bng  = (const float*)d_in[14];
    const float* bnb  = (const float*)d_in[15];
    float* out = (float*)d_out;
    float* ws  = (float*)d_ws;

    // ws_size is constant across calls -> identical launch sequence every call.
    const size_t MONO_BYTES = (size_t)(33816576 + 8650752 + ST_FLOATS) * 4;
    int nch = (ws_size >= MONO_BYTES) ? 1 : 2;
    int chunk = 1024 / nch;
    size_t P1SZ = (size_t)chunk * 256 * 129;

    float* P1c  = ws;                       // [chunk][256][129]
    float* P2   = ws + P1SZ;                // [1024][128][66]
    float* SPA  = ws;                       // [1152][64][128]  (P1c dead)
    float* NF   = ws + 9437184;             // [1152][64][128]  (P2 dead)
    float* GOUT = ws;                       // [1152][64][64]   (SPA dead)
    float* ST   = ws + P1SZ + 8650752;

    hipMemsetAsync((void*)ST, 0, ST_FLOATS * sizeof(float), stream);

    // ---- block 1 stats (CI=64 CO=256 L=256 pad=1) ----
    conv1_k<0><<<dim3(4, 2, 1024), TPB, 0, stream>>>(x, c1w, nullptr, nullptr, nullptr,
                                                     nullptr, ST + RAW1, 0);
    bn_fin_k<<<1, TPB, 0, stream>>>(ST + RAW1, ST + FIN1, 256, 1.0f / 262144.0f);

    // ---- block1 apply + block2 stats, per chunk ----
    for (int c = 0; c < nch; c++) {
        conv1_k<1><<<dim3(4, 2, chunk), TPB, 0, stream>>>(x, c1w, ST + FIN1, g1, b1,
                                                          P1c, nullptr, c * chunk);
        convG_k<0, 0><<<dim3(3, 1, chunk), TPB, 0, stream>>>(P1c, c2w, nullptr, nullptr,
                                                             nullptr, nullptr, ST + RAW2,
                                                             256, 128, 129, 2, 131, 66, 0);
    }
    bn_fin_k<<<1, TPB, 0, stream>>>(ST + RAW2, ST + FIN2, 128, 1.0f / 134144.0f);

    // ---- block2 apply (recompute P1 chunk if chunked) ----
    for (int c = 0; c < nch; c++) {
        if (nch > 1)
            conv1_k<1><<<dim3(4, 2, chunk), TPB, 0, stream>>>(x, c1w, ST + FIN1, g1, b1,
                                                              P1c, nullptr, c * chunk);
        convG_k<1, 0><<<dim3(3, 1, chunk), TPB, 0, stream>>>(P1c, c2w, ST + FIN2, g2, b2,
                                                             P2, nullptr,
                                                             256, 128, 129, 2, 131, 66,
                                                             c * chunk);
    }

    // ---- block 3 (CI=128 CO=256 Lin=66 pad=3, Lout=70, Lp=36) ----
    convG_k<0, 0><<<dim3(2, 2, 1024), TPB, 0, stream>>>(P2, c3w, nullptr, nullptr, nullptr,
                                                        nullptr, ST + RAW3,
                                                        128, 256, 66, 3, 70, 36, 0);
    bn_fin_k<<<1, TPB, 0, stream>>>(ST + RAW3, ST + FIN3, 256, 1.0f / 71680.0f);
    convG_k<1, 1><<<dim3(2, 2, 1024), TPB, 0, stream>>>(P2, c3w, ST + FIN3, g3, b3,
                                                        SPA, nullptr,
                                                        128, 256, 66, 3, 70, 36, 0);

    // ---- graph stage ----
    gemm_nf_k<<<1152, TPB, 0, stream>>>(SPA, mapw, mapb, NF);
    graph_k<<<1152, TPB, 0, stream>>>(NF, thw, thb, GOUT);
    stat_inner_k<<<288, TPB, 0, stream>>>(GOUT, ST + RAWG, 256);
    final_k<<<9216, TPB, 0, stream>>>(GOUT, ST + RAWG, bng, bnb, out);
}

// Round 5
// 18727.351 us; speedup vs baseline: 3.4501x; 3.4501x over previous
//
#include <hip/hip_runtime.h>
#include <hip/hip_bf16.h>

// ---------------------------------------------------------------------------
// MPNN_block_seperate — fp32, high-ILP conv core (round-4 spill fixed).
// Round-4 failure: __launch_bounds__(256,4) capped VGPRs at 64 -> 36-float
// accumulator tile spilled to scratch -> 37 GB HBM traffic per dispatch.
// Fix: __launch_bounds__(256,2) (no spill), LDS weight stride 385 (384 = 0
// mod 32 was a 16-way bank conflict on staging writes).
// ---------------------------------------------------------------------------

#define TPB 256
#define CO_T 128
#define L_T  64
#define CIC  16
#define SWS  (CO_T * 3 + 1)   // 385: bank-conflict-free weight stride

// stats block offsets (floats)
#define RAW1 0
#define FIN1 512
#define RAW2 1024
#define FIN2 1280
#define RAW3 1536
#define FIN3 2048
#define RAWG 2560
#define ST_FLOATS 2688

// ---------------------------------------------------------------------------
// conv1: reads x[bq][s][n][d] directly (in[ci][l] = x[bq][l][n][ci]).
// MODE 0 = stats (raw), MODE 1 = apply (BN+ReLU+pool -> P1 chunk [bl][256][129])
// ---------------------------------------------------------------------------
template<int MODE>
__global__ __launch_bounds__(TPB, 2) void conv1_k(const float* __restrict__ x,
                                                  const float* __restrict__ w,
                                                  const float* __restrict__ fin,
                                                  const float* __restrict__ g,
                                                  const float* __restrict__ bt,
                                                  float* __restrict__ out,
                                                  float* __restrict__ raw,
                                                  int bn0)
{
    __shared__ float s_in[CIC * 68];          //  4352 B
    __shared__ float s_w[CIC * SWS];          // 24640 B
    int bn = bn0 + blockIdx.z;
    int bq = bn >> 6, n = bn & 63;
    int co0 = blockIdx.y * CO_T;
    int l0  = blockIdx.x * L_T;
    int tid = threadIdx.x;
    int lt = tid & 7, cg = tid >> 3;          // 8 l-groups x 32 co-groups
    int ll = lt * 8;
    const float* xb = x + (size_t)bq * 1048576 + (size_t)n * 64;

    float z[4][9] = {};                        // z[c4][k], k -> l = l0+ll+k-1
#pragma unroll 1
    for (int ci0 = 0; ci0 < 64; ci0 += CIC) {
        for (int idx = tid; idx < 68 * 16; idx += TPB) {
            int c = idx & 15, jj = idx >> 4;
            int gl = l0 - 2 + jj;              // pad=1: gl = l0-1-pad+jj
            float v = 0.f;
            if (gl >= 0 && gl < 256) v = xb[(size_t)gl * 4096 + ci0 + c];
            s_in[c * 68 + jj] = v;
        }
        for (int idx = tid; idx < CO_T * 64; idx += TPB) {
            int r = idx & 3;
            if (r < 3) {
                int c = idx >> 6, cc = (idx >> 2) & 15;
                s_w[cc * SWS + c * 3 + r] =
                    w[((size_t)(co0 + c) * 64 + ci0 + cc) * 3 + r];
            }
        }
        __syncthreads();
#pragma unroll
        for (int cc = 0; cc < CIC; cc++) {
            const float* ip = &s_in[cc * 68 + ll];
            float iv[12];
#pragma unroll
            for (int t = 0; t < 12; t += 4) {
                float4 v4 = *(const float4*)(ip + t);
                iv[t] = v4.x; iv[t+1] = v4.y; iv[t+2] = v4.z; iv[t+3] = v4.w;
            }
            const float* wp = &s_w[cc * SWS + cg * 12];
            float wv[12];
#pragma unroll
            for (int t = 0; t < 12; t += 4) {
                float4 v4 = *(const float4*)(wp + t);
                wv[t] = v4.x; wv[t+1] = v4.y; wv[t+2] = v4.z; wv[t+3] = v4.w;
            }
#pragma unroll
            for (int c4 = 0; c4 < 4; c4++)
#pragma unroll
                for (int k = 0; k < 9; k++)
                    z[c4][k] += wv[c4*3] * iv[k] + wv[c4*3+1] * iv[k+1]
                              + wv[c4*3+2] * iv[k+2];
        }
        __syncthreads();
    }
    if (MODE == 0) {
#pragma unroll
        for (int c4 = 0; c4 < 4; c4++) {
            float s1 = 0.f, s2 = 0.f;
#pragma unroll
            for (int k = 1; k < 9; k++) { float v = z[c4][k]; s1 += v; s2 += v * v; }
            s1 += __shfl_xor(s1, 1); s2 += __shfl_xor(s2, 1);
            s1 += __shfl_xor(s1, 2); s2 += __shfl_xor(s2, 2);
            s1 += __shfl_xor(s1, 4); s2 += __shfl_xor(s2, 4);
            if (lt == 0) {
                int co = co0 + cg * 4 + c4;
                atomicAdd(&raw[co], s1);
                atomicAdd(&raw[256 + co], s2);
            }
        }
    } else {
#pragma unroll
        for (int c4 = 0; c4 < 4; c4++) {
            int co = co0 + cg * 4 + c4;
            float scale = g[co] * fin[256 + co];
            float shift = bt[co] - fin[co] * scale;
            float zb[9];
#pragma unroll
            for (int k = 0; k < 9; k++) {
                int lz = l0 + ll + k - 1;
                float v = z[c4][k] * scale + shift;
                v = v > 0.f ? v : 0.f;
                zb[k] = (lz >= 0) ? v : 0.f;
            }
            float* ob = out + ((size_t)blockIdx.z * 256 + co) * 129;
            int jb = (l0 >> 1) + lt * 4;
#pragma unroll
            for (int jj = 0; jj < 4; jj++)
                ob[jb + jj] = fmaxf(zb[2*jj], zb[2*jj+1]);
            if (l0 == 192 && lt == 7)
                ob[128] = zb[8];               // window j=128 uses only z[255]
        }
    }
}

// ---------------------------------------------------------------------------
// generic conv: reads in[b][CI][Lin] fp32.
// MODE 0 = stats; MODE 1 = apply. EPI 0: out[(bn0+bz)*CO+co][Lp];
// EPI 1: fold to spa[((bq*72+tc)*64+n)*128+f], linear=co*36+j.
// ---------------------------------------------------------------------------
template<int MODE, int EPI>
__global__ __launch_bounds__(TPB, 2) void convG_k(const float* __restrict__ in,
                                                  const float* __restrict__ w,
                                                  const float* __restrict__ fin,
                                                  const float* __restrict__ g,
                                                  const float* __restrict__ bt,
                                                  float* __restrict__ out,
                                                  float* __restrict__ raw,
                                                  int CI, int CO, int Lin, int pad,
                                                  int Lout, int Lp, int bn0)
{
    __shared__ float s_in[CIC * 68];
    __shared__ float s_w[CIC * SWS];
    int bz  = blockIdx.z;
    int co0 = blockIdx.y * CO_T;
    int l0  = blockIdx.x * L_T;
    int tid = threadIdx.x;
    int lt = tid & 7, cg = tid >> 3;
    int ll = lt * 8;
    const float* inb = in + (size_t)bz * CI * Lin;

    float z[4][9] = {};
#pragma unroll 1
    for (int ci0 = 0; ci0 < CI; ci0 += CIC) {
        for (int idx = tid; idx < 68 * 16; idx += TPB) {
            int c = idx / 68, jj = idx - c * 68;
            int gl = l0 - 1 - pad + jj;
            float v = 0.f;
            if (gl >= 0 && gl < Lin) v = inb[(size_t)(ci0 + c) * Lin + gl];
            s_in[c * 68 + jj] = v;
        }
        for (int idx = tid; idx < CO_T * 64; idx += TPB) {
            int r = idx & 3;
            if (r < 3) {
                int c = idx >> 6, cc = (idx >> 2) & 15;
                s_w[cc * SWS + c * 3 + r] =
                    w[((size_t)(co0 + c) * CI + ci0 + cc) * 3 + r];
            }
        }
        __syncthreads();
#pragma unroll
        for (int cc = 0; cc < CIC; cc++) {
            const float* ip = &s_in[cc * 68 + ll];
            float iv[12];
#pragma unroll
            for (int t = 0; t < 12; t += 4) {
                float4 v4 = *(const float4*)(ip + t);
                iv[t] = v4.x; iv[t+1] = v4.y; iv[t+2] = v4.z; iv[t+3] = v4.w;
            }
            const float* wp = &s_w[cc * SWS + cg * 12];
            float wv[12];
#pragma unroll
            for (int t = 0; t < 12; t += 4) {
                float4 v4 = *(const float4*)(wp + t);
                wv[t] = v4.x; wv[t+1] = v4.y; wv[t+2] = v4.z; wv[t+3] = v4.w;
            }
#pragma unroll
            for (int c4 = 0; c4 < 4; c4++)
#pragma unroll
                for (int k = 0; k < 9; k++)
                    z[c4][k] += wv[c4*3] * iv[k] + wv[c4*3+1] * iv[k+1]
                              + wv[c4*3+2] * iv[k+2];
        }
        __syncthreads();
    }
    if (MODE == 0) {
#pragma unroll
        for (int c4 = 0; c4 < 4; c4++) {
            float s1 = 0.f, s2 = 0.f;
#pragma unroll
            for (int k = 1; k < 9; k++) {
                int lz = l0 + ll + k - 1;
                if (lz < Lout) { float v = z[c4][k]; s1 += v; s2 += v * v; }
            }
            s1 += __shfl_xor(s1, 1); s2 += __shfl_xor(s2, 1);
            s1 += __shfl_xor(s1, 2); s2 += __shfl_xor(s2, 2);
            s1 += __shfl_xor(s1, 4); s2 += __shfl_xor(s2, 4);
            if (lt == 0) {
                int co = co0 + cg * 4 + c4;
                atomicAdd(&raw[co], s1);
                atomicAdd(&raw[CO + co], s2);
            }
        }
    } else {
#pragma unroll
        for (int c4 = 0; c4 < 4; c4++) {
            int co = co0 + cg * 4 + c4;
            float scale = g[co] * fin[CO + co];
            float shift = bt[co] - fin[co] * scale;
            float zb[8];
#pragma unroll
            for (int k = 0; k < 8; k++) {
                int lz = l0 + ll + k - 1;
                float v = z[c4][k] * scale + shift;
                v = v > 0.f ? v : 0.f;
                zb[k] = (lz >= 0 && lz < Lout) ? v : 0.f;
            }
            int jb = (l0 >> 1) + lt * 4;
#pragma unroll
            for (int jj = 0; jj < 4; jj++) {
                int j = jb + jj;
                if (j >= Lp) continue;
                float v = fmaxf(zb[2*jj], zb[2*jj+1]);
                if (EPI == 0) {
                    out[((size_t)(bn0 + bz) * CO + co) * (size_t)Lp + j] = v;
                } else {
                    int linear = co * 36 + j;
                    int tc = linear >> 7, f = linear & 127;
                    int bq = bz >> 6, n = bz & 63;
                    out[(((size_t)bq * 72 + tc) * 64 + n) * 128 + f] = v;
                }
            }
        }
    }
}

__global__ __launch_bounds__(TPB) void bn_fin_k(const float* __restrict__ raw,
                                                float* __restrict__ fin, int C, float invN)
{
    int c = threadIdx.x + blockIdx.x * TPB;
    if (c < C) {
        float m = raw[c] * invN;
        float v = raw[C + c] * invN - m * m;
        fin[c] = m;
        fin[C + c] = rsqrtf(v + 1e-5f);
    }
}

// ---------------- nf = spa @ map_w^T + map_b ----------------
__global__ __launch_bounds__(TPB) void gemm_nf_k(const float* __restrict__ A,
                                                 const float* __restrict__ W,
                                                 const float* __restrict__ bias,
                                                 float* __restrict__ out)
{
    __shared__ float s_a[64 * 33];
    __shared__ float s_w[128 * 33];
    int r0 = blockIdx.x * 64;
    int tid = threadIdx.x;
    int rg = tid >> 4, cgc = tid & 15;
    float acc[4][8];
#pragma unroll
    for (int i = 0; i < 8; i++) {
        float bv = bias[cgc + 16 * i];
#pragma unroll
        for (int j = 0; j < 4; j++) acc[j][i] = bv;
    }
    for (int k0 = 0; k0 < 128; k0 += 32) {
        for (int idx = tid; idx < 64 * 32; idx += TPB) {
            int r = idx >> 5, kk = idx & 31;
            s_a[r * 33 + kk] = A[(size_t)(r0 + r) * 128 + k0 + kk];
        }
        for (int idx = tid; idx < 128 * 32; idx += TPB) {
            int f = idx >> 5, kk = idx & 31;
            s_w[f * 33 + kk] = W[(size_t)f * 128 + k0 + kk];
        }
        __syncthreads();
#pragma unroll
        for (int kk = 0; kk < 32; kk++) {
            float av[4];
#pragma unroll
            for (int j = 0; j < 4; j++) av[j] = s_a[(rg * 4 + j) * 33 + kk];
#pragma unroll
            for (int i = 0; i < 8; i++) {
                float wv = s_w[(cgc + 16 * i) * 33 + kk];
#pragma unroll
                for (int j = 0; j < 4; j++) acc[j][i] += av[j] * wv;
            }
        }
        __syncthreads();
    }
#pragma unroll
    for (int j = 0; j < 4; j++) {
        size_t row = (size_t)(r0 + rg * 4 + j) * 128;
#pragma unroll
        for (int i = 0; i < 8; i++) out[row + cgc + 16 * i] = acc[j][i];
    }
}

// ---------------- graph kernel (adj/softmax/G/out) per b' slice ----------------
__global__ __launch_bounds__(TPB) void graph_k(const float* __restrict__ nf,
                                               const float* __restrict__ theta_w,
                                               const float* __restrict__ theta_b,
                                               float* __restrict__ gout)
{
    __shared__ float s_nfT[128 * 66];
    __shared__ float s_adj[64 * 64];
    __shared__ float s_red[256];
    __shared__ float s_rmax[64];
    __shared__ float s_rsum[64];
    float* s_G = s_nfT;

    int bp = blockIdx.x;
    int tid = threadIdx.x;
    const float* nfb = nf + (size_t)bp * 64 * 128;

    for (int idx = tid; idx < 64 * 128; idx += TPB) {
        int n = idx >> 7, f = idx & 127;
        s_nfT[f * 66 + n] = nfb[idx];
    }
    __syncthreads();

    int mg = tid & 15, ng = tid >> 4;
    {
        float a[4][4] = {};
#pragma unroll 4
        for (int f = 0; f < 128; f++) {
            float nv[4], mv[4];
#pragma unroll
            for (int j = 0; j < 4; j++) nv[j] = s_nfT[f * 66 + ng * 4 + j];
#pragma unroll
            for (int i = 0; i < 4; i++) mv[i] = s_nfT[f * 66 + mg * 4 + i];
#pragma unroll
            for (int j = 0; j < 4; j++)
#pragma unroll
                for (int i = 0; i < 4; i++) a[j][i] += nv[j] * mv[i];
        }
#pragma unroll
        for (int j = 0; j < 4; j++)
#pragma unroll
            for (int i = 0; i < 4; i++) {
                int n = ng * 4 + j, m = mg * 4 + i;
                float v = a[j][i];
                if (n == m) v -= 1e8f;
                v = v > 0.f ? v : 0.01f * v;
                s_adj[n * 64 + m] = v;
            }
    }
    __syncthreads();
    {
        int n = tid >> 2, q = tid & 3;
        float mx = -3.0e38f;
        for (int m = q * 16; m < q * 16 + 16; m++) mx = fmaxf(mx, s_adj[n * 64 + m]);
        s_red[n * 4 + q] = mx;
    }
    __syncthreads();
    if (tid < 64)
        s_rmax[tid] = fmaxf(fmaxf(s_red[tid * 4], s_red[tid * 4 + 1]),
                            fmaxf(s_red[tid * 4 + 2], s_red[tid * 4 + 3]));
    __syncthreads();
    {
        int n = tid >> 2, q = tid & 3;
        float mx = s_rmax[n];
        float sm = 0.f;
        for (int m = q * 16; m < q * 16 + 16; m++) {
            float e = __expf(s_adj[n * 64 + m] - mx);
            s_adj[n * 64 + m] = e;
            sm += e;
        }
        s_red[n * 4 + q] = sm;
    }
    __syncthreads();
    if (tid < 64)
        s_rsum[tid] = 1.0f / (s_red[tid * 4] + s_red[tid * 4 + 1] +
                              s_red[tid * 4 + 2] + s_red[tid * 4 + 3]);
    __syncthreads();
    {
        int n = tid >> 2, q = tid & 3;
        float inv = s_rsum[n];
        for (int m = q * 16; m < q * 16 + 16; m++)
            s_adj[n * 64 + m] = s_adj[n * 64 + m] * inv + ((n == m) ? 1.f : 0.f);
    }
    __syncthreads();
    {
        float ga[4][4] = {};
#pragma unroll 4
        for (int f = 0; f < 128; f++) {
            float mv[4], tv[4];
#pragma unroll
            for (int j = 0; j < 4; j++) mv[j] = s_nfT[f * 66 + ng * 4 + j];
#pragma unroll
            for (int i = 0; i < 4; i++) tv[i] = theta_w[(size_t)(mg + 16 * i) * 128 + f];
#pragma unroll
            for (int j = 0; j < 4; j++)
#pragma unroll
                for (int i = 0; i < 4; i++) ga[j][i] += mv[j] * tv[i];
        }
        __syncthreads();
#pragma unroll
        for (int j = 0; j < 4; j++)
#pragma unroll
            for (int i = 0; i < 4; i++)
                s_G[(ng * 4 + j) * 66 + mg + 16 * i] = ga[j][i];
    }
    __syncthreads();
    {
        float oacc[4][4];
#pragma unroll
        for (int i = 0; i < 4; i++) {
            float bv = theta_b[mg + 16 * i];
#pragma unroll
            for (int j = 0; j < 4; j++) oacc[j][i] = bv;
        }
#pragma unroll 4
        for (int m = 0; m < 64; m++) {
            float av[4], gv[4];
#pragma unroll
            for (int j = 0; j < 4; j++) av[j] = s_adj[(ng * 4 + j) * 64 + m];
#pragma unroll
            for (int i = 0; i < 4; i++) gv[i] = s_G[m * 66 + mg + 16 * i];
#pragma unroll
            for (int j = 0; j < 4; j++)
#pragma unroll
                for (int i = 0; i < 4; i++) oacc[j][i] += av[j] * gv[i];
        }
        float* gb = gout + (size_t)bp * 64 * 64;
#pragma unroll
        for (int j = 0; j < 4; j++)
#pragma unroll
            for (int i = 0; i < 4; i++)
                gb[(size_t)(ng * 4 + j) * 64 + mg + 16 * i] = oacc[j][i];
    }
}

// ---------------- stats over gout [73728][64] per feature o ----------------
__global__ __launch_bounds__(TPB) void stat_inner_k(const float* __restrict__ y,
                                                    float* __restrict__ raw,
                                                    int rows_per_block)
{
    int tid = threadIdx.x;
    int o = tid & 63, rr = tid >> 6;
    long r0 = (long)blockIdx.x * rows_per_block;
    float s1 = 0.f, s2 = 0.f;
    for (int r = rr; r < rows_per_block; r += 4) {
        float v = y[(r0 + r) * 64 + o];
        s1 += v; s2 += v * v;
    }
    __shared__ float b1[TPB], b2[TPB];
    b1[tid] = s1; b2[tid] = s2; __syncthreads();
    if (tid < 128) { b1[tid] += b1[tid + 128]; b2[tid] += b2[tid + 128]; }
    __syncthreads();
    if (tid < 64) {
        atomicAdd(&raw[o], b1[tid] + b1[tid + 64]);
        atomicAdd(&raw[64 + o], b2[tid] + b2[tid + 64]);
    }
}

// ---------------- final BN + leaky + pair mean -> [16][36][64][64] ----------------
__global__ __launch_bounds__(TPB) void final_k(const float* __restrict__ gout,
                                               const float* __restrict__ raw,
                                               const float* __restrict__ g,
                                               const float* __restrict__ b,
                                               float* __restrict__ out)
{
    long idx = (long)blockIdx.x * TPB + threadIdx.x;
    if (idx >= 2359296L) return;
    int o = (int)(idx & 63);
    long t = idx >> 6;
    int n = (int)(t & 63);
    long t2 = t >> 6;
    long wd = t2 % 36;
    long bb = t2 / 36;
    const float invN = 1.0f / 73728.0f;
    float m = raw[o] * invN;
    float var = raw[64 + o] * invN - m * m;
    float scale = g[o] * rsqrtf(var + 1e-5f);
    float shift = b[o] - m * scale;
    long bp = bb * 72 + wd * 2;
    float v0 = gout[(bp * 64 + n) * 64 + o] * scale + shift;
    float v1 = gout[((bp + 1) * 64 + n) * 64 + o] * scale + shift;
    v0 = v0 > 0.f ? v0 : 0.01f * v0;
    v1 = v1 > 0.f ? v1 : 0.01f * v1;
    out[idx] = 0.5f * (v0 + v1);
}

// ---------------------------------------------------------------------------
extern "C" void kernel_launch(void* const* d_in, const int* in_sizes, int n_in,
                              void* d_out, int out_size, void* d_ws, size_t ws_size,
                              hipStream_t stream)
{
    (void)in_sizes; (void)n_in; (void)out_size;
    const float* x    = (const float*)d_in[0];
    const float* c1w  = (const float*)d_in[1];
    const float* g1   = (const float*)d_in[2];
    const float* b1   = (const float*)d_in[3];
    const float* c2w  = (const float*)d_in[4];
    const float* g2   = (const float*)d_in[5];
    const float* b2   = (const float*)d_in[6];
    const float* c3w  = (const float*)d_in[7];
    const float* g3   = (const float*)d_in[8];
    const float* b3   = (const float*)d_in[9];
    const float* mapw = (const float*)d_in[10];
    const float* mapb = (const float*)d_in[11];
    const float* thw  = (const float*)d_in[12];
    const float* thb  = (const float*)d_in[13];
    const float* bng  = (const float*)d_in[14];
    const float* bnb  = (const float*)d_in[15];
    float* out = (float*)d_out;
    float* ws  = (float*)d_ws;

    // ws_size is constant across calls -> identical launch sequence every call.
    const size_t MONO_BYTES = (size_t)(33816576 + 8650752 + ST_FLOATS) * 4;
    int nch = (ws_size >= MONO_BYTES) ? 1 : 2;
    int chunk = 1024 / nch;
    size_t P1SZ = (size_t)chunk * 256 * 129;

    float* P1c  = ws;                       // [chunk][256][129]
    float* P2   = ws + P1SZ;                // [1024][128][66]
    float* SPA  = ws;                       // [1152][64][128]  (P1c dead)
    float* NF   = ws + 9437184;             // [1152][64][128]  (P2 dead)
    float* GOUT = ws;                       // [1152][64][64]   (SPA dead)
    float* ST   = ws + P1SZ + 8650752;

    hipMemsetAsync((void*)ST, 0, ST_FLOATS * sizeof(float), stream);

    // ---- block 1 stats (CI=64 CO=256 L=256 pad=1) ----
    conv1_k<0><<<dim3(4, 2, 1024), TPB, 0, stream>>>(x, c1w, nullptr, nullptr, nullptr,
                                                     nullptr, ST + RAW1, 0);
    bn_fin_k<<<1, TPB, 0, stream>>>(ST + RAW1, ST + FIN1, 256, 1.0f / 262144.0f);

    // ---- block1 apply + block2 stats, per chunk ----
    for (int c = 0; c < nch; c++) {
        conv1_k<1><<<dim3(4, 2, chunk), TPB, 0, stream>>>(x, c1w, ST + FIN1, g1, b1,
                                                          P1c, nullptr, c * chunk);
        convG_k<0, 0><<<dim3(3, 1, chunk), TPB, 0, stream>>>(P1c, c2w, nullptr, nullptr,
                                                             nullptr, nullptr, ST + RAW2,
                                                             256, 128, 129, 2, 131, 66, 0);
    }
    bn_fin_k<<<1, TPB, 0, stream>>>(ST + RAW2, ST + FIN2, 128, 1.0f / 134144.0f);

    // ---- block2 apply (recompute P1 chunk if chunked) ----
    for (int c = 0; c < nch; c++) {
        if (nch > 1)
            conv1_k<1><<<dim3(4, 2, chunk), TPB, 0, stream>>>(x, c1w, ST + FIN1, g1, b1,
                                                              P1c, nullptr, c * chunk);
        convG_k<1, 0><<<dim3(3, 1, chunk), TPB, 0, stream>>>(P1c, c2w, ST + FIN2, g2, b2,
                                                             P2, nullptr,
                                                             256, 128, 129, 2, 131, 66,
                                                             c * chunk);
    }

    // ---- block 3 (CI=128 CO=256 Lin=66 pad=3, Lout=70, Lp=36) ----
    convG_k<0, 0><<<dim3(2, 2, 1024), TPB, 0, stream>>>(P2, c3w, nullptr, nullptr, nullptr,
                                                        nullptr, ST + RAW3,
                                                        128, 256, 66, 3, 70, 36, 0);
    bn_fin_k<<<1, TPB, 0, stream>>>(ST + RAW3, ST + FIN3, 256, 1.0f / 71680.0f);
    convG_k<1, 1><<<dim3(2, 2, 1024), TPB, 0, stream>>>(P2, c3w, ST + FIN3, g3, b3,
                                                        SPA, nullptr,
                                                        128, 256, 66, 3, 70, 36, 0);

    // ---- graph stage ----
    gemm_nf_k<<<1152, TPB, 0, stream>>>(SPA, mapw, mapb, NF);
    graph_k<<<1152, TPB, 0, stream>>>(NF, thw, thb, GOUT);
    stat_inner_k<<<288, TPB, 0, stream>>>(GOUT, ST + RAWG, 256);
    final_k<<<9216, TPB, 0, stream>>>(GOUT, ST + RAWG, bng, bnb, out);
}

// Round 6
// 9501.205 us; speedup vs baseline: 6.8003x; 1.9711x over previous
//
#include <hip/hip_runtime.h>
#include <hip/hip_bf16.h>

// ---------------------------------------------------------------------------
// MPNN_block_seperate — fp32, register-budget-disciplined conv core.
// Round-5 failure: 36-acc tile -> allocator picked 128 VGPRs + scratch spill
// (13.6 GB HBM/dispatch). Fix: 4co x 5l tile (20 accs, ~40 live operand
// floats), CO_T=64, no min-waves launch_bounds, cc-unroll 4. Target natural
// VGPR ~80-100, zero spill. Orchestration identical to rounds 3/5.
// ---------------------------------------------------------------------------

#define TPB 256
#define CO_T 64
#define L_T  64
#define CIC  16
#define SWS  (CO_T * 3 + 3)   // 195: 195%32=3; staging banks 3cc+r distinct

// stats block offsets (floats)
#define RAW1 0
#define FIN1 512
#define RAW2 1024
#define FIN2 1280
#define RAW3 1536
#define FIN3 2048
#define RAWG 2560
#define ST_FLOATS 2688

// ---------------------------------------------------------------------------
// conv1: reads x[bq][s][n][d] directly (in[ci][l] = x[bq][l][n][ci]); pad=1.
// MODE 0 = stats; MODE 1 = apply (BN+ReLU+pool -> P1 chunk [bl][256][129]).
// Thread tile: 4 co x 5 z (z[k] <-> l = l0 + lt*4 + k - 1).
// ---------------------------------------------------------------------------
template<int MODE>
__global__ __launch_bounds__(TPB) void conv1_k(const float* __restrict__ x,
                                               const float* __restrict__ w,
                                               const float* __restrict__ fin,
                                               const float* __restrict__ g,
                                               const float* __restrict__ bt,
                                               float* __restrict__ out,
                                               float* __restrict__ raw,
                                               int bn0)
{
    __shared__ float s_in[CIC * 68];   //  4352 B ; col jj = in[l0-2+jj]
    __shared__ float s_w[CIC * SWS];   // 12480 B ; [cc][co*3+r]
    int bn = bn0 + blockIdx.z;
    int bq = bn >> 6, n = bn & 63;
    int co0 = blockIdx.y * CO_T;
    int l0  = blockIdx.x * L_T;
    int tid = threadIdx.x;
    int lt = tid & 15, cg = tid >> 4;  // 16 l-groups x 16 co-groups
    int ll = lt * 4;
    const float* xb = x + (size_t)bq * 1048576 + (size_t)n * 64;

    float z[4][5] = {};
#pragma unroll 1
    for (int ci0 = 0; ci0 < 64; ci0 += CIC) {
        for (int idx = tid; idx < 68 * 16; idx += TPB) {
            int c = idx & 15, jj = idx >> 4;
            int gl = l0 - 2 + jj;
            float v = 0.f;
            if (gl >= 0 && gl < 256) v = xb[(size_t)gl * 4096 + ci0 + c];
            s_in[c * 68 + jj] = v;
        }
        for (int idx = tid; idx < CO_T * CIC * 4; idx += TPB) {
            int r = idx & 3;
            if (r < 3) {
                int c = idx >> 6, cc = (idx >> 2) & 15;
                s_w[cc * SWS + c * 3 + r] =
                    w[((size_t)(co0 + c) * 64 + ci0 + cc) * 3 + r];
            }
        }
        __syncthreads();
#pragma unroll 4
        for (int cc = 0; cc < CIC; cc++) {
            const float* ip = &s_in[cc * 68 + ll];
            float4 a4 = *(const float4*)(ip);
            float4 b4 = *(const float4*)(ip + 4);
            float iv[8] = { a4.x, a4.y, a4.z, a4.w, b4.x, b4.y, b4.z, b4.w };
            const float* wp = &s_w[cc * SWS + cg * 12];
            float wv[12];
#pragma unroll
            for (int t = 0; t < 12; t += 4) {
                float4 v4 = *(const float4*)(wp + t);
                wv[t] = v4.x; wv[t+1] = v4.y; wv[t+2] = v4.z; wv[t+3] = v4.w;
            }
#pragma unroll
            for (int c4 = 0; c4 < 4; c4++)
#pragma unroll
                for (int k = 0; k < 5; k++)
                    z[c4][k] += wv[c4*3] * iv[k] + wv[c4*3+1] * iv[k+1]
                              + wv[c4*3+2] * iv[k+2];
        }
        __syncthreads();
    }
    if (MODE == 0) {
#pragma unroll
        for (int c4 = 0; c4 < 4; c4++) {
            float s1 = 0.f, s2 = 0.f;
#pragma unroll
            for (int k = 1; k < 5; k++) { float v = z[c4][k]; s1 += v; s2 += v * v; }
            s1 += __shfl_xor(s1, 1); s2 += __shfl_xor(s2, 1);
            s1 += __shfl_xor(s1, 2); s2 += __shfl_xor(s2, 2);
            s1 += __shfl_xor(s1, 4); s2 += __shfl_xor(s2, 4);
            s1 += __shfl_xor(s1, 8); s2 += __shfl_xor(s2, 8);
            if (lt == 0) {
                int co = co0 + cg * 4 + c4;
                atomicAdd(&raw[co], s1);
                atomicAdd(&raw[256 + co], s2);
            }
        }
    } else {
#pragma unroll
        for (int c4 = 0; c4 < 4; c4++) {
            int co = co0 + cg * 4 + c4;
            float scale = g[co] * fin[256 + co];
            float shift = bt[co] - fin[co] * scale;
            float zb[5];
#pragma unroll
            for (int k = 0; k < 5; k++) {
                int lz = l0 + ll + k - 1;
                float v = z[c4][k] * scale + shift;
                v = v > 0.f ? v : 0.f;
                zb[k] = (lz >= 0) ? v : 0.f;
            }
            float* ob = out + ((size_t)blockIdx.z * 256 + co) * 129;
            int j0 = (l0 >> 1) + lt * 2;
            ob[j0]     = fmaxf(zb[0], zb[1]);
            ob[j0 + 1] = fmaxf(zb[2], zb[3]);
            if (l0 == 192 && lt == 15) ob[128] = zb[4];   // window uses only z[255]
        }
    }
}

// ---------------------------------------------------------------------------
// generic conv: reads in[b][CI][Lin] fp32. MODE 0 stats, MODE 1 apply.
// EPI 0: out[(bn0+bz)*CO+co][Lp];  EPI 1: fold spa[((bq*72+tc)*64+n)*128+f].
// ---------------------------------------------------------------------------
template<int MODE, int EPI>
__global__ __launch_bounds__(TPB) void convG_k(const float* __restrict__ in,
                                               const float* __restrict__ w,
                                               const float* __restrict__ fin,
                                               const float* __restrict__ g,
                                               const float* __restrict__ bt,
                                               float* __restrict__ out,
                                               float* __restrict__ raw,
                                               int CI, int CO, int Lin, int pad,
                                               int Lout, int Lp, int bn0)
{
    __shared__ float s_in[CIC * 68];   // col jj = in[l0-1-pad+jj]
    __shared__ float s_w[CIC * SWS];
    int bz  = blockIdx.z;
    int co0 = blockIdx.y * CO_T;
    int l0  = blockIdx.x * L_T;
    int tid = threadIdx.x;
    int lt = tid & 15, cg = tid >> 4;
    int ll = lt * 4;
    const float* inb = in + (size_t)bz * CI * Lin;

    float z[4][5] = {};
#pragma unroll 1
    for (int ci0 = 0; ci0 < CI; ci0 += CIC) {
        for (int idx = tid; idx < 68 * 16; idx += TPB) {
            int c = idx / 68, jj = idx - c * 68;
            int gl = l0 - 1 - pad + jj;
            float v = 0.f;
            if (gl >= 0 && gl < Lin) v = inb[(size_t)(ci0 + c) * Lin + gl];
            s_in[c * 68 + jj] = v;
        }
        for (int idx = tid; idx < CO_T * CIC * 4; idx += TPB) {
            int r = idx & 3;
            if (r < 3) {
                int c = idx >> 6, cc = (idx >> 2) & 15;
                s_w[cc * SWS + c * 3 + r] =
                    w[((size_t)(co0 + c) * CI + ci0 + cc) * 3 + r];
            }
        }
        __syncthreads();
#pragma unroll 4
        for (int cc = 0; cc < CIC; cc++) {
            const float* ip = &s_in[cc * 68 + ll];
            float4 a4 = *(const float4*)(ip);
            float4 b4 = *(const float4*)(ip + 4);
            float iv[8] = { a4.x, a4.y, a4.z, a4.w, b4.x, b4.y, b4.z, b4.w };
            const float* wp = &s_w[cc * SWS + cg * 12];
            float wv[12];
#pragma unroll
            for (int t = 0; t < 12; t += 4) {
                float4 v4 = *(const float4*)(wp + t);
                wv[t] = v4.x; wv[t+1] = v4.y; wv[t+2] = v4.z; wv[t+3] = v4.w;
            }
#pragma unroll
            for (int c4 = 0; c4 < 4; c4++)
#pragma unroll
                for (int k = 0; k < 5; k++)
                    z[c4][k] += wv[c4*3] * iv[k] + wv[c4*3+1] * iv[k+1]
                              + wv[c4*3+2] * iv[k+2];
        }
        __syncthreads();
    }
    if (MODE == 0) {
#pragma unroll
        for (int c4 = 0; c4 < 4; c4++) {
            float s1 = 0.f, s2 = 0.f;
#pragma unroll
            for (int k = 1; k < 5; k++) {
                int lz = l0 + ll + k - 1;
                if (lz < Lout) { float v = z[c4][k]; s1 += v; s2 += v * v; }
            }
            s1 += __shfl_xor(s1, 1); s2 += __shfl_xor(s2, 1);
            s1 += __shfl_xor(s1, 2); s2 += __shfl_xor(s2, 2);
            s1 += __shfl_xor(s1, 4); s2 += __shfl_xor(s2, 4);
            s1 += __shfl_xor(s1, 8); s2 += __shfl_xor(s2, 8);
            if (lt == 0) {
                int co = co0 + cg * 4 + c4;
                atomicAdd(&raw[co], s1);
                atomicAdd(&raw[CO + co], s2);
            }
        }
    } else {
#pragma unroll
        for (int c4 = 0; c4 < 4; c4++) {
            int co = co0 + cg * 4 + c4;
            float scale = g[co] * fin[CO + co];
            float shift = bt[co] - fin[co] * scale;
            float zb[4];
#pragma unroll
            for (int k = 0; k < 4; k++) {
                int lz = l0 + ll + k - 1;
                float v = z[c4][k] * scale + shift;
                v = v > 0.f ? v : 0.f;
                zb[k] = (lz >= 0 && lz < Lout) ? v : 0.f;
            }
            int j0 = (l0 >> 1) + lt * 2;
            float v0 = fmaxf(zb[0], zb[1]);
            float v1 = fmaxf(zb[2], zb[3]);
            if (EPI == 0) {
                size_t row = ((size_t)(bn0 + bz) * CO + co) * (size_t)Lp;
                if (j0 < Lp)     out[row + j0]     = v0;
                if (j0 + 1 < Lp) out[row + j0 + 1] = v1;
            } else {
                int bq = bz >> 6, nn = bz & 63;
#pragma unroll
                for (int q = 0; q < 2; q++) {
                    int j = j0 + q;
                    if (j < 36) {
                        int linear = co * 36 + j;
                        int tc = linear >> 7, f = linear & 127;
                        out[(((size_t)bq * 72 + tc) * 64 + nn) * 128 + f] = q ? v1 : v0;
                    }
                }
            }
        }
    }
}

__global__ __launch_bounds__(TPB) void bn_fin_k(const float* __restrict__ raw,
                                                float* __restrict__ fin, int C, float invN)
{
    int c = threadIdx.x + blockIdx.x * TPB;
    if (c < C) {
        float m = raw[c] * invN;
        float v = raw[C + c] * invN - m * m;
        fin[c] = m;
        fin[C + c] = rsqrtf(v + 1e-5f);
    }
}

// ---------------- nf = spa @ map_w^T + map_b ----------------
__global__ __launch_bounds__(TPB) void gemm_nf_k(const float* __restrict__ A,
                                                 const float* __restrict__ W,
                                                 const float* __restrict__ bias,
                                                 float* __restrict__ out)
{
    __shared__ float s_a[64 * 33];
    __shared__ float s_w[128 * 33];
    int r0 = blockIdx.x * 64;
    int tid = threadIdx.x;
    int rg = tid >> 4, cgc = tid & 15;
    float acc[4][8];
#pragma unroll
    for (int i = 0; i < 8; i++) {
        float bv = bias[cgc + 16 * i];
#pragma unroll
        for (int j = 0; j < 4; j++) acc[j][i] = bv;
    }
    for (int k0 = 0; k0 < 128; k0 += 32) {
        for (int idx = tid; idx < 64 * 32; idx += TPB) {
            int r = idx >> 5, kk = idx & 31;
            s_a[r * 33 + kk] = A[(size_t)(r0 + r) * 128 + k0 + kk];
        }
        for (int idx = tid; idx < 128 * 32; idx += TPB) {
            int f = idx >> 5, kk = idx & 31;
            s_w[f * 33 + kk] = W[(size_t)f * 128 + k0 + kk];
        }
        __syncthreads();
#pragma unroll
        for (int kk = 0; kk < 32; kk++) {
            float av[4];
#pragma unroll
            for (int j = 0; j < 4; j++) av[j] = s_a[(rg * 4 + j) * 33 + kk];
#pragma unroll
            for (int i = 0; i < 8; i++) {
                float wv = s_w[(cgc + 16 * i) * 33 + kk];
#pragma unroll
                for (int j = 0; j < 4; j++) acc[j][i] += av[j] * wv;
            }
        }
        __syncthreads();
    }
#pragma unroll
    for (int j = 0; j < 4; j++) {
        size_t row = (size_t)(r0 + rg * 4 + j) * 128;
#pragma unroll
        for (int i = 0; i < 8; i++) out[row + cgc + 16 * i] = acc[j][i];
    }
}

// ---------------- graph kernel (adj/softmax/G/out) per b' slice ----------------
__global__ __launch_bounds__(TPB) void graph_k(const float* __restrict__ nf,
                                               const float* __restrict__ theta_w,
                                               const float* __restrict__ theta_b,
                                               float* __restrict__ gout)
{
    __shared__ float s_nfT[128 * 66];
    __shared__ float s_adj[64 * 64];
    __shared__ float s_red[256];
    __shared__ float s_rmax[64];
    __shared__ float s_rsum[64];
    float* s_G = s_nfT;

    int bp = blockIdx.x;
    int tid = threadIdx.x;
    const float* nfb = nf + (size_t)bp * 64 * 128;

    for (int idx = tid; idx < 64 * 128; idx += TPB) {
        int n = idx >> 7, f = idx & 127;
        s_nfT[f * 66 + n] = nfb[idx];
    }
    __syncthreads();

    int mg = tid & 15, ng = tid >> 4;
    {
        float a[4][4] = {};
#pragma unroll 4
        for (int f = 0; f < 128; f++) {
            float nv[4], mv[4];
#pragma unroll
            for (int j = 0; j < 4; j++) nv[j] = s_nfT[f * 66 + ng * 4 + j];
#pragma unroll
            for (int i = 0; i < 4; i++) mv[i] = s_nfT[f * 66 + mg * 4 + i];
#pragma unroll
            for (int j = 0; j < 4; j++)
#pragma unroll
                for (int i = 0; i < 4; i++) a[j][i] += nv[j] * mv[i];
        }
#pragma unroll
        for (int j = 0; j < 4; j++)
#pragma unroll
            for (int i = 0; i < 4; i++) {
                int n = ng * 4 + j, m = mg * 4 + i;
                float v = a[j][i];
                if (n == m) v -= 1e8f;
                v = v > 0.f ? v : 0.01f * v;
                s_adj[n * 64 + m] = v;
            }
    }
    __syncthreads();
    {
        int n = tid >> 2, q = tid & 3;
        float mx = -3.0e38f;
        for (int m = q * 16; m < q * 16 + 16; m++) mx = fmaxf(mx, s_adj[n * 64 + m]);
        s_red[n * 4 + q] = mx;
    }
    __syncthreads();
    if (tid < 64)
        s_rmax[tid] = fmaxf(fmaxf(s_red[tid * 4], s_red[tid * 4 + 1]),
                            fmaxf(s_red[tid * 4 + 2], s_red[tid * 4 + 3]));
    __syncthreads();
    {
        int n = tid >> 2, q = tid & 3;
        float mx = s_rmax[n];
        float sm = 0.f;
        for (int m = q * 16; m < q * 16 + 16; m++) {
            float e = __expf(s_adj[n * 64 + m] - mx);
            s_adj[n * 64 + m] = e;
            sm += e;
        }
        s_red[n * 4 + q] = sm;
    }
    __syncthreads();
    if (tid < 64)
        s_rsum[tid] = 1.0f / (s_red[tid * 4] + s_red[tid * 4 + 1] +
                              s_red[tid * 4 + 2] + s_red[tid * 4 + 3]);
    __syncthreads();
    {
        int n = tid >> 2, q = tid & 3;
        float inv = s_rsum[n];
        for (int m = q * 16; m < q * 16 + 16; m++)
            s_adj[n * 64 + m] = s_adj[n * 64 + m] * inv + ((n == m) ? 1.f : 0.f);
    }
    __syncthreads();
    {
        float ga[4][4] = {};
#pragma unroll 4
        for (int f = 0; f < 128; f++) {
            float mv[4], tv[4];
#pragma unroll
            for (int j = 0; j < 4; j++) mv[j] = s_nfT[f * 66 + ng * 4 + j];
#pragma unroll
            for (int i = 0; i < 4; i++) tv[i] = theta_w[(size_t)(mg + 16 * i) * 128 + f];
#pragma unroll
            for (int j = 0; j < 4; j++)
#pragma unroll
                for (int i = 0; i < 4; i++) ga[j][i] += mv[j] * tv[i];
        }
        __syncthreads();
#pragma unroll
        for (int j = 0; j < 4; j++)
#pragma unroll
            for (int i = 0; i < 4; i++)
                s_G[(ng * 4 + j) * 66 + mg + 16 * i] = ga[j][i];
    }
    __syncthreads();
    {
        float oacc[4][4];
#pragma unroll
        for (int i = 0; i < 4; i++) {
            float bv = theta_b[mg + 16 * i];
#pragma unroll
            for (int j = 0; j < 4; j++) oacc[j][i] = bv;
        }
#pragma unroll 4
        for (int m = 0; m < 64; m++) {
            float av[4], gv[4];
#pragma unroll
            for (int j = 0; j < 4; j++) av[j] = s_adj[(ng * 4 + j) * 64 + m];
#pragma unroll
            for (int i = 0; i < 4; i++) gv[i] = s_G[m * 66 + mg + 16 * i];
#pragma unroll
            for (int j = 0; j < 4; j++)
#pragma unroll
                for (int i = 0; i < 4; i++) oacc[j][i] += av[j] * gv[i];
        }
        float* gb = gout + (size_t)bp * 64 * 64;
#pragma unroll
        for (int j = 0; j < 4; j++)
#pragma unroll
            for (int i = 0; i < 4; i++)
                gb[(size_t)(ng * 4 + j) * 64 + mg + 16 * i] = oacc[j][i];
    }
}

// ---------------- stats over gout [73728][64] per feature o ----------------
__global__ __launch_bounds__(TPB) void stat_inner_k(const float* __restrict__ y,
                                                    float* __restrict__ raw,
                                                    int rows_per_block)
{
    int tid = threadIdx.x;
    int o = tid & 63, rr = tid >> 6;
    long r0 = (long)blockIdx.x * rows_per_block;
    float s1 = 0.f, s2 = 0.f;
    for (int r = rr; r < rows_per_block; r += 4) {
        float v = y[(r0 + r) * 64 + o];
        s1 += v; s2 += v * v;
    }
    __shared__ float b1[TPB], b2[TPB];
    b1[tid] = s1; b2[tid] = s2; __syncthreads();
    if (tid < 128) { b1[tid] += b1[tid + 128]; b2[tid] += b2[tid + 128]; }
    __syncthreads();
    if (tid < 64) {
        atomicAdd(&raw[o], b1[tid] + b1[tid + 64]);
        atomicAdd(&raw[64 + o], b2[tid] + b2[tid + 64]);
    }
}

// ---------------- final BN + leaky + pair mean -> [16][36][64][64] ----------------
__global__ __launch_bounds__(TPB) void final_k(const float* __restrict__ gout,
                                               const float* __restrict__ raw,
                                               const float* __restrict__ g,
                                               const float* __restrict__ b,
                                               float* __restrict__ out)
{
    long idx = (long)blockIdx.x * TPB + threadIdx.x;
    if (idx >= 2359296L) return;
    int o = (int)(idx & 63);
    long t = idx >> 6;
    int n = (int)(t & 63);
    long t2 = t >> 6;
    long wd = t2 % 36;
    long bb = t2 / 36;
    const float invN = 1.0f / 73728.0f;
    float m = raw[o] * invN;
    float var = raw[64 + o] * invN - m * m;
    float scale = g[o] * rsqrtf(var + 1e-5f);
    float shift = b[o] - m * scale;
    long bp = bb * 72 + wd * 2;
    float v0 = gout[(bp * 64 + n) * 64 + o] * scale + shift;
    float v1 = gout[((bp + 1) * 64 + n) * 64 + o] * scale + shift;
    v0 = v0 > 0.f ? v0 : 0.01f * v0;
    v1 = v1 > 0.f ? v1 : 0.01f * v1;
    out[idx] = 0.5f * (v0 + v1);
}

// ---------------------------------------------------------------------------
extern "C" void kernel_launch(void* const* d_in, const int* in_sizes, int n_in,
                              void* d_out, int out_size, void* d_ws, size_t ws_size,
                              hipStream_t stream)
{
    (void)in_sizes; (void)n_in; (void)out_size;
    const float* x    = (const float*)d_in[0];
    const float* c1w  = (const float*)d_in[1];
    const float* g1   = (const float*)d_in[2];
    const float* b1   = (const float*)d_in[3];
    const float* c2w  = (const float*)d_in[4];
    const float* g2   = (const float*)d_in[5];
    const float* b2   = (const float*)d_in[6];
    const float* c3w  = (const float*)d_in[7];
    const float* g3   = (const float*)d_in[8];
    const float* b3   = (const float*)d_in[9];
    const float* mapw = (const float*)d_in[10];
    const float* mapb = (const float*)d_in[11];
    const float* thw  = (const float*)d_in[12];
    const float* thb  = (const float*)d_in[13];
    const float* bng  = (const float*)d_in[14];
    const float* bnb  = (const float*)d_in[15];
    float* out = (float*)d_out;
    float* ws  = (float*)d_ws;

    // ws_size is constant across calls -> identical launch sequence every call.
    const size_t MONO_BYTES = (size_t)(33816576 + 8650752 + ST_FLOATS) * 4;
    int nch = (ws_size >= MONO_BYTES) ? 1 : 2;
    int chunk = 1024 / nch;
    size_t P1SZ = (size_t)chunk * 256 * 129;

    float* P1c  = ws;                       // [chunk][256][129]
    float* P2   = ws + P1SZ;                // [1024][128][66]
    float* SPA  = ws;                       // [1152][64][128]  (P1c dead)
    float* NF   = ws + 9437184;             // [1152][64][128]  (P2 dead when written)
    float* GOUT = ws;                       // [1152][64][64]   (SPA dead)
    float* ST   = ws + P1SZ + 8650752;

    hipMemsetAsync((void*)ST, 0, ST_FLOATS * sizeof(float), stream);

    // ---- block 1 stats (CI=64 CO=256 L=256 pad=1) ----
    conv1_k<0><<<dim3(4, 4, 1024), TPB, 0, stream>>>(x, c1w, nullptr, nullptr, nullptr,
                                                     nullptr, ST + RAW1, 0);
    bn_fin_k<<<1, TPB, 0, stream>>>(ST + RAW1, ST + FIN1, 256, 1.0f / 262144.0f);

    // ---- block1 apply + block2 stats, per chunk ----
    for (int c = 0; c < nch; c++) {
        conv1_k<1><<<dim3(4, 4, chunk), TPB, 0, stream>>>(x, c1w, ST + FIN1, g1, b1,
                                                          P1c, nullptr, c * chunk);
        convG_k<0, 0><<<dim3(3, 2, chunk), TPB, 0, stream>>>(P1c, c2w, nullptr, nullptr,
                                                             nullptr, nullptr, ST + RAW2,
                                                             256, 128, 129, 2, 131, 66, 0);
    }
    bn_fin_k<<<1, TPB, 0, stream>>>(ST + RAW2, ST + FIN2, 128, 1.0f / 134144.0f);

    // ---- block2 apply (recompute P1 chunk if chunked) ----
    for (int c = 0; c < nch; c++) {
        if (nch > 1)
            conv1_k<1><<<dim3(4, 4, chunk), TPB, 0, stream>>>(x, c1w, ST + FIN1, g1, b1,
                                                              P1c, nullptr, c * chunk);
        convG_k<1, 0><<<dim3(3, 2, chunk), TPB, 0, stream>>>(P1c, c2w, ST + FIN2, g2, b2,
                                                             P2, nullptr,
                                                             256, 128, 129, 2, 131, 66,
                                                             c * chunk);
    }

    // ---- block 3 (CI=128 CO=256 Lin=66 pad=3, Lout=70, Lp=36) ----
    convG_k<0, 0><<<dim3(2, 4, 1024), TPB, 0, stream>>>(P2, c3w, nullptr, nullptr, nullptr,
                                                        nullptr, ST + RAW3,
                                                        128, 256, 66, 3, 70, 36, 0);
    bn_fin_k<<<1, TPB, 0, stream>>>(ST + RAW3, ST + FIN3, 256, 1.0f / 71680.0f);
    convG_k<1, 1><<<dim3(2, 4, 1024), TPB, 0, stream>>>(P2, c3w, ST + FIN3, g3, b3,
                                                        SPA, nullptr,
                                                        128, 256, 66, 3, 70, 36, 0);

    // ---- graph stage ----
    gemm_nf_k<<<1152, TPB, 0, stream>>>(SPA, mapw, mapb, NF);
    graph_k<<<1152, TPB, 0, stream>>>(NF, thw, thb, GOUT);
    stat_inner_k<<<288, TPB, 0, stream>>>(GOUT, ST + RAWG, 256);
    final_k<<<9216, TPB, 0, stream>>>(GOUT, ST + RAWG, bng, bnb, out);
}